// Round 4
// baseline (160.969 us; speedup 1.0000x reference)
//
#include <hip/hip_runtime.h>
#include <cstdint>
#include <climits>

#pragma clang fp contract(off)

#define NCAM 6
#define NCLS 10
#define NKEY 60          // cam*10+cls
#define IMGW 1600
#define IMGH 900
#define CS_MAX 512       // max dets staged per chunk (LDS)

// XLA-style float->int32: saturate out-of-range, NaN -> 0. (Verified R3: absmax 0.)
__device__ __forceinline__ int sat_f2i(float f) {
    if (f != f) return 0;
    if (f >= 2147483648.0f) return INT_MAX;
    if (f <= -2147483648.0f) return INT_MIN;
    return (int)f;
}

// ---------------- Kernel 1: stable counting sort of dets by (cam*10+cls) ----
// Single block, 256 threads. Invalid dets (batch!=0, cam/label out of range)
// are dropped (their reference contribution is exactly 0).
// Output: sdet[pos][8] = {x1,y1,x2,y2,area,score,0,0}, seg[61] bucket offsets.
__global__ __launch_bounds__(256) void sort_kernel(
        const float4* __restrict__ det_boxes,
        const int*    __restrict__ det_labels,
        const float*  __restrict__ det_scores,
        const int*    __restrict__ det_batch,
        const int*    __restrict__ det_cam,
        float*        __restrict__ sdet,      // [M][8]
        int*          __restrict__ seg,       // [61]
        unsigned int* __restrict__ keyrank,   // [M] temp
        int M) {
    __shared__ unsigned int hist[NKEY * 256];
    __shared__ unsigned int tot[NKEY];
    __shared__ int kb[NKEY + 1];
    int t = threadIdx.x;
    for (int k = t; k < NKEY * 256; k += 256) hist[k] = 0u;
    __syncthreads();

    int per = (M + 255) >> 8;
    int b0 = t * per, b1 = min(b0 + per, M);
    for (int m = b0; m < b1; m++) {
        int cam = det_cam[m], bi = det_batch[m], cls = det_labels[m] - 1;
        bool ok = (bi == 0) && (cam >= 0) && (cam < NCAM) && (cls >= 0) && (cls < NCLS);
        if (ok) {
            int key = cam * NCLS + cls;
            unsigned int r = hist[key * 256 + t];
            hist[key * 256 + t] = r + 1u;
            keyrank[m] = ((unsigned int)key << 16) | r;   // rank < 65536
        } else {
            keyrank[m] = 0xFFFFFFFFu;
        }
    }
    __syncthreads();

    // per-key exclusive prefix over threads (thread b owns key b)
    if (t < NKEY) {
        unsigned int run = 0;
        for (int j = 0; j < 256; j++) {
            unsigned int v = hist[t * 256 + j];
            hist[t * 256 + j] = run;
            run += v;
        }
        tot[t] = run;
    }
    __syncthreads();
    if (t == 0) {
        int base = 0;
        for (int k = 0; k < NKEY; k++) { kb[k] = base; seg[k] = base; base += (int)tot[k]; }
        kb[NKEY] = base; seg[NKEY] = base;
    }
    __syncthreads();

    for (int m = b0; m < b1; m++) {
        unsigned int v = keyrank[m];
        if (v == 0xFFFFFFFFu) continue;
        int key = (int)(v >> 16);
        int pos = kb[key] + (int)hist[key * 256 + t] + (int)(v & 0xFFFFu);
        float4 b = det_boxes[m];
        float area = (b.z - b.x) * (b.w - b.y);
        float4* o = (float4*)(sdet + (size_t)pos * 8);
        o[0] = b;
        o[1] = make_float4(area, det_scores[m], 0.0f, 0.0f);
    }
}

// ---------------- Kernel 2: projection, comp-major output ------------------
// projW[(cam*6+comp)*N + n], comp = {x1,y1,x2,y2,area,valid}
__global__ __launch_bounds__(256) void proj_kernel(
        const float* __restrict__ boxes,   // [N][7]
        const float* __restrict__ ia,      // [6][4][4]
        const float* __restrict__ la,      // [4][4]
        const float* __restrict__ l2i,     // [6][4][4]
        float* __restrict__ projW,
        int N) {
    int n = blockIdx.x * 256 + threadIdx.x;
    if (n >= N) return;
    float bx = boxes[n*7+0], by = boxes[n*7+1], bz = boxes[n*7+2];
    float dx = boxes[n*7+3], dy = boxes[n*7+4], dz = boxes[n*7+5];
    float yaw = boxes[n*7+6];
    float c = (float)cos((double)yaw);   // correctly-rounded trig (validated R3)
    float s = (float)sin((double)yaw);

    float a00=la[0],a01=la[1],a02=la[2],t0=la[3];
    float a10=la[4],a11=la[5],a12=la[6],t1=la[7];
    float a20=la[8],a21=la[9],a22=la[10],t2=la[11];
    float det = a00*(a11*a22-a12*a21) - a01*(a10*a22-a12*a20) + a02*(a10*a21-a11*a20);
    float id = 1.0f/det;
    float r00=(a11*a22-a12*a21)*id, r01=(a02*a21-a01*a22)*id, r02=(a01*a12-a02*a11)*id;
    float r10=(a12*a20-a10*a22)*id, r11=(a00*a22-a02*a20)*id, r12=(a02*a10-a00*a12)*id;
    float r20=(a10*a21-a11*a20)*id, r21=(a01*a20-a00*a21)*id, r22=(a00*a11-a01*a10)*id;

    float PX[8], PY[8], PZ[8];
    #pragma unroll
    for (int k = 0; k < 8; k++) {
        float sx = ((k==0||k==1||k==4||k==5) ?  0.5f : -0.5f) * dx;
        float sy = ((k==0||k==3||k==4||k==7) ?  0.5f : -0.5f) * dy;
        float sz = ((k>=4)                   ?  0.5f : -0.5f) * dz;
        float cx = sx*c - sy*s + bx;
        float cy = sx*s + sy*c + by;
        float cz = sz + bz;
        float ux = cx - t0, uy = cy - t1, uz = cz - t2;
        PX[k] = r00*ux + r01*uy + r02*uz;
        PY[k] = r10*ux + r11*uy + r12*uz;
        PZ[k] = r20*ux + r21*uy + r22*uz;
    }

    for (int cam = 0; cam < NCAM; cam++) {
        const float* L = l2i + cam*16;
        const float* A = ia  + cam*16;
        int minx = INT_MAX, miny = INT_MAX, maxx = INT_MIN, maxy = INT_MIN;
        #pragma unroll
        for (int k = 0; k < 8; k++) {
            float u = L[0]*PX[k] + L[1]*PY[k] + L[2]*PZ[k]  + L[3];
            float v = L[4]*PX[k] + L[5]*PY[k] + L[6]*PZ[k]  + L[7];
            float w = L[8]*PX[k] + L[9]*PY[k] + L[10]*PZ[k] + L[11];
            float zc = fminf(fmaxf(w, 1e-5f), 100000.0f);
            float x = u / zc, y = v / zc;
            float xx = A[0]*x + A[1]*y + A[2]*zc + A[3];
            float yy = A[4]*x + A[5]*y + A[6]*zc + A[7];
            int pxi = sat_f2i(xx); pxi = min(max(pxi, 0), IMGW);
            int pyi = sat_f2i(yy); pyi = min(max(pyi, 0), IMGH);
            minx = min(minx, pxi); maxx = max(maxx, pxi);
            miny = min(miny, pyi); maxy = max(maxy, pyi);
        }
        float x1 = (float)minx, y1 = (float)miny, x2 = (float)maxx, y2 = (float)maxy;
        float validf = ((x2 - x1) > 0.0f && (y2 - y1) > 0.0f) ? 1.0f : 0.0f;
        projW[(cam*6+0)*N + n] = x1;
        projW[(cam*6+1)*N + n] = y1;
        projW[(cam*6+2)*N + n] = x2;
        projW[(cam*6+3)*N + n] = y2;
        projW[(cam*6+4)*N + n] = (x2 - x1) * (y2 - y1);
        projW[(cam*6+5)*N + n] = validf;
    }
}

// ---------------- Kernel 3: main accumulation ------------------------------
// grid = (ceil(N/256), S). Thread = one box; block chunk = dets [c0,c1) of the
// sorted stream. Det stream is wave-uniform (broadcast LDS reads). (cam,cls)
// constant per segment -> scalar accumulator, flushed to LDS probs row.
__global__ __launch_bounds__(256, 4) void main_kernel(
        const float* __restrict__ projW,
        const float* __restrict__ sdet,   // [M][8] sorted
        const int*   __restrict__ seg,    // [61]
        float*       __restrict__ partial,// [S][10][N]
        int N, int M, int CS) {
    int tid = threadIdx.x;
    int box = blockIdx.x * 256 + tid;
    int chunk = blockIdx.y;
    int c0 = chunk * CS, c1 = min(c0 + CS, M);

    __shared__ float4 sd[CS_MAX * 2];
    __shared__ int sseg[NKEY + 1];
    __shared__ float sprobs[256 * 11];   // stride 11: gcd(11,32)=1, conflict-free

    int nst = (c1 - c0) * 2;
    const float4* gsd = (const float4*)sdet;
    for (int i = tid; i < nst; i += 256) sd[i] = gsd[(size_t)c0 * 2 + i];
    if (tid <= NKEY) sseg[tid] = seg[tid];
    #pragma unroll
    for (int k = 0; k < 11; k++) sprobs[tid * 11 + k] = 0.0f;
    __syncthreads();

    if (box < N) {
        for (int cam = 0; cam < NCAM; cam++) {
            int kb = cam * NCLS;
            int sA = max(sseg[kb], c0), eA = min(sseg[kb + NCLS], c1);
            if (sA >= eA) continue;
            float Px1 = projW[(cam*6+0)*N + box];
            float Py1 = projW[(cam*6+1)*N + box];
            float Px2 = projW[(cam*6+2)*N + box];
            float Py2 = projW[(cam*6+3)*N + box];
            float Pa  = projW[(cam*6+4)*N + box];
            float Pv  = projW[(cam*6+5)*N + box];
            for (int cls = 0; cls < NCLS; cls++) {
                int s = max(sseg[kb + cls], c0), e = min(sseg[kb + cls + 1], c1);
                if (s >= e) continue;
                float acc = 0.0f;
                const float4* dp = &sd[(s - c0) * 2];
                for (int m = s; m < e; m++) {
                    float4 b = dp[0];
                    float4 q = dp[1];
                    dp += 2;
                    float ltx = fmaxf(b.x, Px1);
                    float lty = fmaxf(b.y, Py1);
                    float rbx = fminf(b.z, Px2);
                    float rby = fminf(b.w, Py2);
                    float iw = fmaxf(rbx - ltx, 0.0f);
                    float ih = fmaxf(rby - lty, 0.0f);
                    float inter = iw * ih;
                    float uni = (q.x + Pa) - inter;
                    float r = __fdividef(inter, uni);
                    float iou = (uni > 0.0f) ? r : 0.0f;
                    acc += iou * q.y;
                }
                sprobs[tid * 11 + cls] += acc * Pv;
            }
        }
        #pragma unroll
        for (int k = 0; k < NCLS; k++)
            partial[((size_t)chunk * NCLS + k) * N + box] = sprobs[tid * 11 + k];
    }
}

// ---------------- Kernel 4: reduce over chunks + argmax --------------------
__global__ __launch_bounds__(256) void reduce_kernel(
        const float* __restrict__ partial,
        const float* __restrict__ projW,
        float* __restrict__ out, int N, int S) {
    int n = blockIdx.x * 256 + threadIdx.x;
    if (n >= N) return;
    float p[NCLS];
    #pragma unroll
    for (int k = 0; k < NCLS; k++) p[k] = 0.0f;
    for (int c = 0; c < S; c++) {
        #pragma unroll
        for (int k = 0; k < NCLS; k++)
            p[k] += partial[((size_t)c * NCLS + k) * N + n];
    }
    float nv = 0.0f;
    #pragma unroll
    for (int cam = 0; cam < NCAM; cam++) nv += projW[(cam*6+5)*N + n];
    float denom = 1e-5f + nv;
    float best = -1e30f; int bk = 0;
    #pragma unroll
    for (int k = 0; k < NCLS; k++) {
        float v = p[k] / denom;
        if (v > best) { best = v; bk = k; }   // strict >: first-max (jnp.argmax)
    }
    out[n]     = (float)(bk + 1);
    out[N + n] = best;
}

extern "C" void kernel_launch(void* const* d_in, const int* in_sizes, int n_in,
                              void* d_out, int out_size, void* d_ws, size_t ws_size,
                              hipStream_t stream) {
    const float*  pred_boxes = (const float*)d_in[0];
    const float*  ia         = (const float*)d_in[1];
    const float*  la         = (const float*)d_in[2];
    const float*  l2i        = (const float*)d_in[3];
    const float4* det_boxes  = (const float4*)d_in[4];
    const int*    det_labels = (const int*)d_in[5];
    const float*  det_scores = (const float*)d_in[6];
    const int*    det_batch  = (const int*)d_in[7];
    const int*    det_cam    = (const int*)d_in[8];
    float* out = (float*)d_out;

    int N = in_sizes[0] / 7;   // 4096
    int M = in_sizes[4] / 4;   // 6144

    // chunking: S chunks of CS dets, CS <= CS_MAX
    int S = 32;
    int CS = (M + S - 1) / S;
    if (CS > CS_MAX) { S = (M + CS_MAX - 1) / CS_MAX; CS = (M + S - 1) / S; }

    // ws layout (16B-aligned slabs)
    char* w = (char*)d_ws;
    float*        sdet    = (float*)w;                              // M*8 floats
    size_t off = (size_t)M * 8 * 4;
    int*          seg     = (int*)(w + off);                        // 61 ints
    off += 256;
    unsigned int* keyrank = (unsigned int*)(w + off);               // M uints
    off += (size_t)M * 4;
    off = (off + 15) & ~(size_t)15;
    float*        projW   = (float*)(w + off);                      // 36*N floats
    off += (size_t)36 * N * 4;
    float*        partial = (float*)(w + off);                      // S*10*N floats

    int gx = (N + 255) / 256;
    sort_kernel<<<1, 256, 0, stream>>>(det_boxes, det_labels, det_scores,
                                       det_batch, det_cam, sdet, seg, keyrank, M);
    proj_kernel<<<gx, 256, 0, stream>>>(pred_boxes, ia, la, l2i, projW, N);
    main_kernel<<<dim3(gx, S), 256, 0, stream>>>(projW, sdet, seg, partial, N, M, CS);
    reduce_kernel<<<gx, 256, 0, stream>>>(partial, projW, out, N, S);
}

// Round 5
// 118.562 us; speedup vs baseline: 1.3577x; 1.3577x over previous
//
#include <hip/hip_runtime.h>
#include <cstdint>
#include <climits>

#pragma clang fp contract(off)

#define NCAM 6
#define NCLS 10
#define NKEY 60          // cam*10+cls
#define IMGW 1600
#define IMGH 900
#define CAP 1024         // slab stride per key (dets); avg occupancy ~102
#define STAGE 512        // dets staged per LDS pass in main kernel

// XLA-style float->int32: saturate out-of-range, NaN -> 0. (Verified R3/R4.)
__device__ __forceinline__ int sat_f2i(float f) {
    if (f != f) return 0;
    if (f >= 2147483648.0f) return INT_MAX;
    if (f <= -2147483648.0f) return INT_MIN;
    return (int)f;
}

// ---------------- K1: prep = projection (blocks 0..PB-1) + bucketing -------
// Bucket block k (blocks PB..PB+59): coalesced scan of all dets, stable
// ballot-prefix compaction of dets with key k into slab[k*CAP..], cnt[k].
__global__ __launch_bounds__(256) void prep_kernel(
        const float*  __restrict__ boxes,   // [N][7]
        const float*  __restrict__ ia,      // [6][4][4]
        const float*  __restrict__ la,      // [4][4]
        const float*  __restrict__ l2i,     // [6][4][4]
        const float4* __restrict__ det_boxes,
        const int*    __restrict__ det_labels,
        const float*  __restrict__ det_scores,
        const int*    __restrict__ det_batch,
        const int*    __restrict__ det_cam,
        float* __restrict__ projW,          // [36][N] comp-major
        float* __restrict__ slab,           // [60][CAP][8]
        int*   __restrict__ cnt,            // [60]
        int N, int M, int PB) {
    int tid = threadIdx.x;

    if ((int)blockIdx.x < PB) {
        // ---- projection (validated R3/R4 math) ----
        int n = blockIdx.x * 256 + tid;
        if (n >= N) return;
        float bx = boxes[n*7+0], by = boxes[n*7+1], bz = boxes[n*7+2];
        float dx = boxes[n*7+3], dy = boxes[n*7+4], dz = boxes[n*7+5];
        float yaw = boxes[n*7+6];
        float c = (float)cos((double)yaw);
        float s = (float)sin((double)yaw);

        float a00=la[0],a01=la[1],a02=la[2],t0=la[3];
        float a10=la[4],a11=la[5],a12=la[6],t1=la[7];
        float a20=la[8],a21=la[9],a22=la[10],t2=la[11];
        float det = a00*(a11*a22-a12*a21) - a01*(a10*a22-a12*a20) + a02*(a10*a21-a11*a20);
        float id = 1.0f/det;
        float r00=(a11*a22-a12*a21)*id, r01=(a02*a21-a01*a22)*id, r02=(a01*a12-a02*a11)*id;
        float r10=(a12*a20-a10*a22)*id, r11=(a00*a22-a02*a20)*id, r12=(a02*a10-a00*a12)*id;
        float r20=(a10*a21-a11*a20)*id, r21=(a01*a20-a00*a21)*id, r22=(a00*a11-a01*a10)*id;

        float PX[8], PY[8], PZ[8];
        #pragma unroll
        for (int k = 0; k < 8; k++) {
            float sx = ((k==0||k==1||k==4||k==5) ?  0.5f : -0.5f) * dx;
            float sy = ((k==0||k==3||k==4||k==7) ?  0.5f : -0.5f) * dy;
            float sz = ((k>=4)                   ?  0.5f : -0.5f) * dz;
            float cx = sx*c - sy*s + bx;
            float cy = sx*s + sy*c + by;
            float cz = sz + bz;
            float ux = cx - t0, uy = cy - t1, uz = cz - t2;
            PX[k] = r00*ux + r01*uy + r02*uz;
            PY[k] = r10*ux + r11*uy + r12*uz;
            PZ[k] = r20*ux + r21*uy + r22*uz;
        }
        for (int cam = 0; cam < NCAM; cam++) {
            const float* L = l2i + cam*16;
            const float* A = ia  + cam*16;
            int minx = INT_MAX, miny = INT_MAX, maxx = INT_MIN, maxy = INT_MIN;
            #pragma unroll
            for (int k = 0; k < 8; k++) {
                float u = L[0]*PX[k] + L[1]*PY[k] + L[2]*PZ[k]  + L[3];
                float v = L[4]*PX[k] + L[5]*PY[k] + L[6]*PZ[k]  + L[7];
                float w = L[8]*PX[k] + L[9]*PY[k] + L[10]*PZ[k] + L[11];
                float zc = fminf(fmaxf(w, 1e-5f), 100000.0f);
                float x = u / zc, y = v / zc;
                float xx = A[0]*x + A[1]*y + A[2]*zc + A[3];
                float yy = A[4]*x + A[5]*y + A[6]*zc + A[7];
                int pxi = sat_f2i(xx); pxi = min(max(pxi, 0), IMGW);
                int pyi = sat_f2i(yy); pyi = min(max(pyi, 0), IMGH);
                minx = min(minx, pxi); maxx = max(maxx, pxi);
                miny = min(miny, pyi); maxy = max(maxy, pyi);
            }
            float x1 = (float)minx, y1 = (float)miny, x2 = (float)maxx, y2 = (float)maxy;
            float validf = ((x2 - x1) > 0.0f && (y2 - y1) > 0.0f) ? 1.0f : 0.0f;
            projW[(cam*6+0)*N + n] = x1;
            projW[(cam*6+1)*N + n] = y1;
            projW[(cam*6+2)*N + n] = x2;
            projW[(cam*6+3)*N + n] = y2;
            projW[(cam*6+4)*N + n] = (x2 - x1) * (y2 - y1);
            projW[(cam*6+5)*N + n] = validf;
        }
        return;
    }

    // ---- bucketing: block owns key k ----
    int k = (int)blockIdx.x - PB;
    int cam = k / NCLS, cls = k % NCLS;
    __shared__ int wcnt[4];
    __shared__ int running;
    if (tid == 0) running = 0;
    int lane = tid & 63, w = tid >> 6;
    __syncthreads();

    for (int c = 0; c < M; c += 256) {
        int m = c + tid;
        bool pred = false;
        if (m < M) {
            int dc = det_cam[m], db = det_batch[m], dl = det_labels[m] - 1;
            pred = (db == 0) && (dc == cam) && (dl == cls);
        }
        unsigned long long ball = __ballot(pred);
        if (lane == 0) wcnt[w] = __popcll(ball);
        __syncthreads();                       // wcnt + prev 'running' visible
        int base = running;
        int pre = 0;
        #pragma unroll
        for (int j = 0; j < 4; j++) pre += (j < w) ? wcnt[j] : 0;
        int tot = wcnt[0] + wcnt[1] + wcnt[2] + wcnt[3];
        if (pred) {
            int pos = base + pre + __popcll(ball & ((1ull << lane) - 1ull));
            float4 b = det_boxes[m];
            float area = (b.z - b.x) * (b.w - b.y);
            float4* o = (float4*)(slab + ((size_t)k * CAP + pos) * 8);
            o[0] = b;
            o[1] = make_float4(area, det_scores[m], 0.0f, 0.0f);
        }
        __syncthreads();                       // all reads of 'running' done
        if (tid == 0) running += tot;
    }
    __syncthreads();
    if (tid == 0) cnt[k] = running;
}

// ---------------- K2: main accumulation ------------------------------------
// grid (ceil(N/256), 60). Block (bx,k): 256 boxes vs bucket k. Dets staged in
// LDS, broadcast-read (same-address b128 -> conflict-free). cls block-uniform
// -> single scalar accumulator.
__global__ __launch_bounds__(256) void main_kernel(
        const float* __restrict__ projW,
        const float* __restrict__ slab,
        const int*   __restrict__ cnt,
        float*       __restrict__ partial,   // [60][N]
        int N) {
    int tid = threadIdx.x;
    int k = blockIdx.y;
    int cam = k / NCLS;
    int box = blockIdx.x * 256 + tid;
    __shared__ float4 sd[STAGE * 2];

    int nk = cnt[k];
    float Px1 = 0, Py1 = 0, Px2 = 0, Py2 = 0, Pa = 0, Pv = 0;
    if (box < N) {
        Px1 = projW[(cam*6+0)*N + box];
        Py1 = projW[(cam*6+1)*N + box];
        Px2 = projW[(cam*6+2)*N + box];
        Py2 = projW[(cam*6+3)*N + box];
        Pa  = projW[(cam*6+4)*N + box];
        Pv  = projW[(cam*6+5)*N + box];
    }
    float acc = 0.0f;
    const float4* gsl = (const float4*)slab;

    for (int base = 0; base < nk; base += STAGE) {
        int cc = min(STAGE, nk - base);
        __syncthreads();
        for (int i = tid; i < cc * 2; i += 256)
            sd[i] = gsl[((size_t)k * CAP + base) * 2 + i];
        __syncthreads();
        if (box < N) {
            for (int m = 0; m < cc; m++) {
                float4 b = sd[2*m];
                float4 q = sd[2*m+1];
                float ltx = fmaxf(b.x, Px1);
                float lty = fmaxf(b.y, Py1);
                float rbx = fminf(b.z, Px2);
                float rby = fminf(b.w, Py2);
                float iw = fmaxf(rbx - ltx, 0.0f);
                float ih = fmaxf(rby - lty, 0.0f);
                float inter = iw * ih;
                float uni = (q.x + Pa) - inter;
                float r = __fdividef(inter, uni);
                float iou = (uni > 0.0f) ? r : 0.0f;
                acc += iou * q.y;
            }
        }
    }
    if (box < N) partial[(size_t)k * N + box] = acc * Pv;
}

// ---------------- K3: reduce over keys + argmax ----------------------------
__global__ __launch_bounds__(256) void reduce_kernel(
        const float* __restrict__ partial,
        const float* __restrict__ projW,
        float* __restrict__ out, int N) {
    int n = blockIdx.x * 256 + threadIdx.x;
    if (n >= N) return;
    float p[NCLS];
    #pragma unroll
    for (int c = 0; c < NCLS; c++) p[c] = 0.0f;
    #pragma unroll
    for (int cam = 0; cam < NCAM; cam++)
        #pragma unroll
        for (int c = 0; c < NCLS; c++)
            p[c] += partial[(size_t)(cam * NCLS + c) * N + n];
    float nv = 0.0f;
    #pragma unroll
    for (int cam = 0; cam < NCAM; cam++) nv += projW[(cam*6+5)*N + n];
    float denom = 1e-5f + nv;
    float best = -1e30f; int bk = 0;
    #pragma unroll
    for (int c = 0; c < NCLS; c++) {
        float v = p[c] / denom;
        if (v > best) { best = v; bk = c; }   // strict >: first-max (jnp.argmax)
    }
    out[n]     = (float)(bk + 1);
    out[N + n] = best;
}

extern "C" void kernel_launch(void* const* d_in, const int* in_sizes, int n_in,
                              void* d_out, int out_size, void* d_ws, size_t ws_size,
                              hipStream_t stream) {
    const float*  pred_boxes = (const float*)d_in[0];
    const float*  ia         = (const float*)d_in[1];
    const float*  la         = (const float*)d_in[2];
    const float*  l2i        = (const float*)d_in[3];
    const float4* det_boxes  = (const float4*)d_in[4];
    const int*    det_labels = (const int*)d_in[5];
    const float*  det_scores = (const float*)d_in[6];
    const int*    det_batch  = (const int*)d_in[7];
    const int*    det_cam    = (const int*)d_in[8];
    float* out = (float*)d_out;

    int N = in_sizes[0] / 7;   // 4096
    int M = in_sizes[4] / 4;   // 6144
    int PB = (N + 255) / 256;  // projection blocks

    // ws layout (16B-aligned slabs)
    char* w = (char*)d_ws;
    float* slab    = (float*)w;                               // 60*CAP*8 floats
    size_t off = (size_t)NKEY * CAP * 8 * 4;
    float* projW   = (float*)(w + off);                       // 36*N floats
    off += (size_t)36 * N * 4;
    float* partial = (float*)(w + off);                       // 60*N floats
    off += (size_t)NKEY * N * 4;
    int*   cnt     = (int*)(w + off);                         // 60 ints

    prep_kernel<<<PB + NKEY, 256, 0, stream>>>(pred_boxes, ia, la, l2i,
                                               det_boxes, det_labels, det_scores,
                                               det_batch, det_cam,
                                               projW, slab, cnt, N, M, PB);
    main_kernel<<<dim3(PB, NKEY), 256, 0, stream>>>(projW, slab, cnt, partial, N);
    reduce_kernel<<<PB, 256, 0, stream>>>(partial, projW, out, N);
}